// Round 3
// baseline (284.613 us; speedup 1.0000x reference)
//
#include <hip/hip_runtime.h>
#include <hip/hip_bf16.h>

#define GAT_ALPHA 0.2f

typedef short bf16x8 __attribute__((ext_vector_type(8)));
typedef float f32x4 __attribute__((ext_vector_type(4)));

__device__ __forceinline__ unsigned f2bf_u(float x) {
  union { float f; unsigned u; } v; v.f = x;
  return (v.u + 0x7fffu + ((v.u >> 16) & 1u)) >> 16;  // RNE to bf16
}
__device__ __forceinline__ unsigned short f2bf(float x) { return (unsigned short)f2bf_u(x); }

// ---------------- kernel 0: W (512x256 f32) -> WT bf16 (256x512) ----------
__global__ void k_wt(const float* __restrict__ W, unsigned short* __restrict__ WT) {
  int kb = blockIdx.x * 8;       // 64 blocks
  int f = threadIdx.x;           // 256 threads = one f each
  bf16x8 o;
#pragma unroll
  for (int i = 0; i < 8; ++i) o[i] = (short)f2bf(W[(kb + i) * 256 + f]);
  *reinterpret_cast<bf16x8*>(WT + f * 512 + kb) = o;
}

// ---------------- kernel 1: WhT = (h@W)^T bf16 [b][f][n], + exp(f1/f2) ----
// Grid 512 (8 b x 64 node-groups of 32), 256 thr (4 waves).
// Wave tile: 64 f x 32 n. C row = f, col = node.
__global__ __launch_bounds__(256, 4) void k_gemm1(
    const float* __restrict__ h, const unsigned short* __restrict__ WT,
    const float* __restrict__ avec,
    unsigned short* __restrict__ WhT,
    float* __restrict__ E1p, float* __restrict__ E1n,
    float* __restrict__ E2p, float* __restrict__ E2n)
{
  const int bx = blockIdx.x;
  const int b = bx & 7, ng = bx >> 3;
  const int n0 = ng * 32;
  const int t = threadIdx.x;
  const int lane = t & 63, w = t >> 6;
  const int l15 = lane & 15, q = lane >> 4;

  __shared__ __align__(16) unsigned short Wt[256 * 36];  // [f][36] pad
  __shared__ float f1a[32], f2a[32];
  if (t < 32) { f1a[t] = 0.f; f2a[t] = 0.f; }

  f32x4 acc[4][2];
#pragma unroll
  for (int i = 0; i < 4; ++i)
#pragma unroll
    for (int j = 0; j < 2; ++j) acc[i][j] = (f32x4){0.f, 0.f, 0.f, 0.f};

  const size_t hbase = ((size_t)(b * 2048 + n0)) * 512;

#pragma unroll 2
  for (int k0 = 0; k0 < 512; k0 += 32) {
    bf16x8 af[4];
#pragma unroll
    for (int mt = 0; mt < 4; ++mt)
      af[mt] = *reinterpret_cast<const bf16x8*>(WT + (w * 64 + mt * 16 + l15) * 512 + k0 + q * 8);
    bf16x8 bfr[2];
#pragma unroll
    for (int nt = 0; nt < 2; ++nt) {
      const float* hp = h + hbase + (size_t)(nt * 16 + l15) * 512 + k0 + q * 8;
      float4 x0 = *reinterpret_cast<const float4*>(hp);
      float4 x1 = *reinterpret_cast<const float4*>(hp + 4);
      bf16x8 bb;
      bb[0] = (short)f2bf(x0.x); bb[1] = (short)f2bf(x0.y);
      bb[2] = (short)f2bf(x0.z); bb[3] = (short)f2bf(x0.w);
      bb[4] = (short)f2bf(x1.x); bb[5] = (short)f2bf(x1.y);
      bb[6] = (short)f2bf(x1.z); bb[7] = (short)f2bf(x1.w);
      bfr[nt] = bb;
    }
#pragma unroll
    for (int mt = 0; mt < 4; ++mt)
#pragma unroll
      for (int nt = 0; nt < 2; ++nt)
        acc[mt][nt] = __builtin_amdgcn_mfma_f32_16x16x32_bf16(af[mt], bfr[nt], acc[mt][nt], 0, 0, 0);
  }

  // stage into LDS [f][n] + f1/f2 partials
  float s1[2] = {0.f, 0.f}, s2[2] = {0.f, 0.f};
#pragma unroll
  for (int mt = 0; mt < 4; ++mt) {
#pragma unroll
    for (int nt = 0; nt < 2; ++nt) {
#pragma unroll
      for (int r = 0; r < 4; ++r) {
        int f = w * 64 + mt * 16 + q * 4 + r;
        float v = acc[mt][nt][r];
        Wt[f * 36 + nt * 16 + l15] = f2bf(v);
        s1[nt] += v * avec[f];
        s2[nt] += v * avec[256 + f];
      }
    }
  }
#pragma unroll
  for (int nt = 0; nt < 2; ++nt) {
    s1[nt] += __shfl_xor(s1[nt], 16); s1[nt] += __shfl_xor(s1[nt], 32);
    s2[nt] += __shfl_xor(s2[nt], 16); s2[nt] += __shfl_xor(s2[nt], 32);
  }
  __syncthreads();   // Wt visible, f1a/f2a init visible
  if (q == 0) {
#pragma unroll
    for (int nt = 0; nt < 2; ++nt) {
      atomicAdd(&f1a[nt * 16 + l15], s1[nt]);
      atomicAdd(&f2a[nt * 16 + l15], s2[nt]);
    }
  }
  // WhT stores: 8-byte lanes, 64-B segments per f-row
#pragma unroll
  for (int i = 0; i < 8; ++i) {
    int f = i * 32 + (t >> 3), g = t & 7;
    uint2 v = *reinterpret_cast<const uint2*>(Wt + f * 36 + g * 4);
    *reinterpret_cast<uint2*>(WhT + (size_t)(b * 256 + f) * 2048 + n0 + g * 4) = v;
  }
  __syncthreads();   // atomics complete
  if (t < 32) {
    int n = b * 2048 + n0 + t;
    float f1 = f1a[t], f2 = f2a[t];
    E1p[n] = __expf(f1);
    E1n[n] = __expf(GAT_ALPHA * f1);
    E2p[n] = __expf(f2);
    E2n[n] = __expf(GAT_ALPHA * f2);
  }
}

// build one A-fragment (8 cols of one row) and write it in fragment layout
__device__ __forceinline__ void build_frag(
    unsigned short* dst, int4 alo, int4 ahi, float e1p, float e1n,
    float4 epl, float4 eph, float4 enl, float4 enh, float& den)
{
  float p0 = alo.x ? fmaxf(e1p * epl.x, e1n * enl.x) : 0.f;
  float p1 = alo.y ? fmaxf(e1p * epl.y, e1n * enl.y) : 0.f;
  float p2 = alo.z ? fmaxf(e1p * epl.z, e1n * enl.z) : 0.f;
  float p3 = alo.w ? fmaxf(e1p * epl.w, e1n * enl.w) : 0.f;
  float p4 = ahi.x ? fmaxf(e1p * eph.x, e1n * enh.x) : 0.f;
  float p5 = ahi.y ? fmaxf(e1p * eph.y, e1n * enh.y) : 0.f;
  float p6 = ahi.z ? fmaxf(e1p * eph.z, e1n * enh.z) : 0.f;
  float p7 = ahi.w ? fmaxf(e1p * eph.w, e1n * enh.w) : 0.f;
  den += ((p0 + p1) + (p2 + p3)) + ((p4 + p5) + (p6 + p7));
  uint4 pk;
  pk.x = f2bf_u(p0) | (f2bf_u(p1) << 16);
  pk.y = f2bf_u(p2) | (f2bf_u(p3) << 16);
  pk.z = f2bf_u(p4) | (f2bf_u(p5) << 16);
  pk.w = f2bf_u(p6) | (f2bf_u(p7) << 16);
  *reinterpret_cast<uint4*>(dst) = pk;
}

// ---------------- kernel 2: masked-softmax(P) @ Wh (unnormalized partials)
// JS slices of the j dimension. Grid 256*JS, 512 thr, 2 blocks/CU.
// P stored in LDS in MFMA A-fragment layout: slot (rt*4+ks)*64+lane, 16B each.
template<int JS>
__global__ __launch_bounds__(512, 4) void k_gat(
    const int* __restrict__ adj, const unsigned short* __restrict__ WhT,
    const float* __restrict__ E1p, const float* __restrict__ E1n,
    const float* __restrict__ E2p, const float* __restrict__ E2n,
    float* __restrict__ num0, float* __restrict__ num1, float* __restrict__ denp)
{
  const int NCH = 16 / JS;
  const int bx = blockIdx.x;
  const int b = bx & 7;
  const int rest = bx >> 3;
  const int js = (JS == 2) ? (rest & 1) : 0;
  const int ig = (JS == 2) ? (rest >> 1) : rest;
  const int i0 = ig * 64;
  const int j00 = js * (NCH * 128);

  const int t = threadIdx.x;
  const int lane = t & 63, w = t >> 6;
  const int l15 = lane & 15, q = lane >> 4;
  const int m = t & 15, qk = (t >> 4) & 3, pp = t >> 6;
  const int rt0 = pp >> 2, ks = pp & 3;
  const int r0 = rt0 * 16 + m, r1 = r0 + 32;
  const int cb = ks * 32 + qk * 8;

  __shared__ __align__(16) unsigned short Pb[2][8192];  // 16 frags x 64 lanes x 16B
  __shared__ float den_l[64];
  if (t < 64) den_l[t] = 0.f;

  const float e1p0 = E1p[b * 2048 + i0 + r0], e1n0 = E1n[b * 2048 + i0 + r0];
  const float e1p1 = E1p[b * 2048 + i0 + r1], e1n1 = E1n[b * 2048 + i0 + r1];
  float d0 = 0.f, d1 = 0.f;

  f32x4 acc[4][2];
#pragma unroll
  for (int i = 0; i < 4; ++i)
#pragma unroll
    for (int j = 0; j < 2; ++j) acc[i][j] = (f32x4){0.f, 0.f, 0.f, 0.f};

  const size_t adj0 = ((size_t)(b * 2048 + i0 + r0)) * 2048 + j00 + cb;
  const size_t adj1 = adj0 + (size_t)32 * 2048;
  const int e2b = b * 2048 + j00 + cb;
  const unsigned short* Wb = WhT + (size_t)(b * 256 + w * 32) * 2048 + j00;

  // ---- prologue: construct chunk 0
  {
    int4 a0l = *reinterpret_cast<const int4*>(adj + adj0);
    int4 a0h = *reinterpret_cast<const int4*>(adj + adj0 + 4);
    int4 a1l = *reinterpret_cast<const int4*>(adj + adj1);
    int4 a1h = *reinterpret_cast<const int4*>(adj + adj1 + 4);
    float4 epl = *reinterpret_cast<const float4*>(E2p + e2b);
    float4 eph = *reinterpret_cast<const float4*>(E2p + e2b + 4);
    float4 enl = *reinterpret_cast<const float4*>(E2n + e2b);
    float4 enh = *reinterpret_cast<const float4*>(E2n + e2b + 4);
    build_frag(&Pb[0][(pp * 64 + lane) * 8], a0l, a0h, e1p0, e1n0, epl, eph, enl, enh, d0);
    build_frag(&Pb[0][((pp + 8) * 64 + lane) * 8], a1l, a1h, e1p1, e1n1, epl, eph, enl, enh, d1);
  }

  for (int c = 0; c < NCH; ++c) {
    __syncthreads();
    // prefetch adj for chunk c+1 (in flight across MFMA section)
    int4 na0l, na0h, na1l, na1h;
    if (c + 1 < NCH) {
      int o = (c + 1) * 128;
      na0l = *reinterpret_cast<const int4*>(adj + adj0 + o);
      na0h = *reinterpret_cast<const int4*>(adj + adj0 + o + 4);
      na1l = *reinterpret_cast<const int4*>(adj + adj1 + o);
      na1h = *reinterpret_cast<const int4*>(adj + adj1 + o + 4);
    }
    // B fragments for chunk c (L2-resident WhT)
    bf16x8 bfr[2][4];
#pragma unroll
    for (int ct = 0; ct < 2; ++ct)
#pragma unroll
      for (int k2 = 0; k2 < 4; ++k2)
        bfr[ct][k2] = *reinterpret_cast<const bf16x8*>(
            Wb + (size_t)(ct * 16 + l15) * 2048 + c * 128 + k2 * 32 + q * 8);
    // MFMA on chunk c: conflict-free b128 fragment reads
    const unsigned short* pb = &Pb[c & 1][0];
#pragma unroll
    for (int k2 = 0; k2 < 4; ++k2) {
      bf16x8 afr[4];
#pragma unroll
      for (int rt = 0; rt < 4; ++rt)
        afr[rt] = *reinterpret_cast<const bf16x8*>(pb + ((rt * 4 + k2) * 64 + lane) * 8);
#pragma unroll
      for (int rt = 0; rt < 4; ++rt)
#pragma unroll
        for (int ct = 0; ct < 2; ++ct)
          acc[rt][ct] = __builtin_amdgcn_mfma_f32_16x16x32_bf16(afr[rt], bfr[ct][k2], acc[rt][ct], 0, 0, 0);
    }
    // construct chunk c+1 (e2 loads are L1/L2-hot broadcasts)
    if (c + 1 < NCH) {
      int o = (c + 1) * 128;
      float4 epl = *reinterpret_cast<const float4*>(E2p + e2b + o);
      float4 eph = *reinterpret_cast<const float4*>(E2p + e2b + o + 4);
      float4 enl = *reinterpret_cast<const float4*>(E2n + e2b + o);
      float4 enh = *reinterpret_cast<const float4*>(E2n + e2b + o + 4);
      unsigned short* wb = &Pb[(c + 1) & 1][0];
      build_frag(wb + (pp * 64 + lane) * 8, na0l, na0h, e1p0, e1n0, epl, eph, enl, enh, d0);
      build_frag(wb + ((pp + 8) * 64 + lane) * 8, na1l, na1h, e1p1, e1n1, epl, eph, enl, enh, d1);
    }
  }

  // denominator: sum over qk lanes (bits 4,5), then 4 waves atomically combine
  d0 += __shfl_xor(d0, 16); d0 += __shfl_xor(d0, 32);
  d1 += __shfl_xor(d1, 16); d1 += __shfl_xor(d1, 32);
  if (lane < 16) {
    atomicAdd(&den_l[r0], d0);
    atomicAdd(&den_l[r1], d1);
  }
  __syncthreads();

  float* nout = (JS == 2 && js == 1) ? num1 : num0;
#pragma unroll
  for (int rt = 0; rt < 4; ++rt) {
#pragma unroll
    for (int r = 0; r < 4; ++r) {
      int row = rt * 16 + q * 4 + r;
      size_t ob = ((size_t)(b * 2048 + i0 + row)) * 256 + w * 32;
#pragma unroll
      for (int ct = 0; ct < 2; ++ct)
        nout[ob + ct * 16 + l15] = acc[rt][ct][r];
    }
  }
  if (t < 64) denp[js * 16384 + b * 2048 + i0 + t] = den_l[t];
}

// ---------------- kernel 3: out = elu(num/den), combine JS slices ---------
// out has 4,194,304 floats = 1,048,576 float4. Grid 2048 x 256 thr x 2 reps.
template<int JS>
__global__ __launch_bounds__(256) void k_fin(
    const float* __restrict__ n0p, const float* __restrict__ n1p,
    const float* __restrict__ denp, float* __restrict__ out)
{
  int i = blockIdx.x * 256 + threadIdx.x;
#pragma unroll
  for (int rep = 0; rep < 2; ++rep) {
    int i4 = i + rep * 524288;                 // float4 index, < 1,048,576
    float4 v = reinterpret_cast<const float4*>(n0p)[i4];
    float dn = denp[i4 >> 6];
    if (JS == 2) {
      float4 u = reinterpret_cast<const float4*>(n1p)[i4];
      v.x += u.x; v.y += u.y; v.z += u.z; v.w += u.w;
      dn += denp[16384 + (i4 >> 6)];
    }
    float id = 1.0f / dn;
    float4 o;
    float x;
    x = v.x * id; o.x = x > 0.f ? x : (__expf(x) - 1.f);
    x = v.y * id; o.y = x > 0.f ? x : (__expf(x) - 1.f);
    x = v.z * id; o.z = x > 0.f ? x : (__expf(x) - 1.f);
    x = v.w * id; o.w = x > 0.f ? x : (__expf(x) - 1.f);
    reinterpret_cast<float4*>(out)[i4] = o;
  }
}

extern "C" void kernel_launch(void* const* d_in, const int* in_sizes, int n_in,
                              void* d_out, int out_size, void* d_ws, size_t ws_size,
                              hipStream_t stream) {
  const float* h   = (const float*)d_in[0];   // [8,2048,512] f32
  const int*   adj = (const int*)d_in[1];     // [8,2048,2048] i32
  const float* W   = (const float*)d_in[2];   // [512,256] f32
  const float* a   = (const float*)d_in[3];   // [512,1] f32
  float* out = (float*)d_out;                 // [8,2048,256] f32

  char* ws = (char*)d_ws;
  unsigned short* WhT = (unsigned short*)ws;                  // 8 MB   [8][256][2048] bf16
  unsigned short* WT  = (unsigned short*)(ws + 8388608);      // 256 KB [256][512] bf16
  float* E1p  = (float*)(ws + 8388608 + 262144);              // 64 KB each
  float* E1n  = E1p + 16384;
  float* E2p  = E1n + 16384;
  float* E2n  = E2p + 16384;
  float* denp = E2n + 16384;                                  // 128 KB [2][16384]
  float* num1 = denp + 2 * 16384;                             // 16 MB  [8][2048][256] f32

  const size_t need2 = 8388608ull + 262144 + 4 * 65536 + 131072 + 16777216;
  const bool js2 = (ws_size >= need2);

  k_wt<<<dim3(64), dim3(256), 0, stream>>>(W, WT);
  k_gemm1<<<dim3(512), dim3(256), 0, stream>>>(h, WT, a, WhT, E1p, E1n, E2p, E2n);
  if (js2) {
    k_gat<2><<<dim3(512), dim3(512), 0, stream>>>(adj, WhT, E1p, E1n, E2p, E2n, out, num1, denp);
    k_fin<2><<<dim3(2048), dim3(256), 0, stream>>>(out, num1, denp, out);
  } else {
    k_gat<1><<<dim3(256), dim3(512), 0, stream>>>(adj, WhT, E1p, E1n, E2p, E2n, out, num1, denp);
    k_fin<1><<<dim3(2048), dim3(256), 0, stream>>>(out, num1, denp, out);
  }
}

// Round 4
// 262.301 us; speedup vs baseline: 1.0851x; 1.0851x over previous
//
#include <hip/hip_runtime.h>
#include <hip/hip_bf16.h>

#define GAT_ALPHA 0.2f

typedef short bf16x8 __attribute__((ext_vector_type(8)));
typedef float f32x4 __attribute__((ext_vector_type(4)));

__device__ __forceinline__ unsigned f2bf_u(float x) {
  union { float f; unsigned u; } v; v.f = x;
  return (v.u + 0x7fffu + ((v.u >> 16) & 1u)) >> 16;  // RNE to bf16
}
__device__ __forceinline__ unsigned short f2bf(float x) { return (unsigned short)f2bf_u(x); }

// ---------------- kernel 0: W (512x256 f32) -> WT bf16 (256x512) ----------
__global__ void k_wt(const float* __restrict__ W, unsigned short* __restrict__ WT) {
  int kb = blockIdx.x * 8;       // 64 blocks
  int f = threadIdx.x;           // 256 threads = one f each
  bf16x8 o;
#pragma unroll
  for (int i = 0; i < 8; ++i) o[i] = (short)f2bf(W[(kb + i) * 256 + f]);
  *reinterpret_cast<bf16x8*>(WT + f * 512 + kb) = o;
}

// ---------------- kernel 1: WhT = (h@W)^T bf16 [b][f][n], + exp(f1/f2) ----
// Grid 512 (8 b x 64 node-groups of 32), 256 thr (4 waves).
// Barrier-free K-loop, register pipeline: WT depth-1, h depth-2.
__global__ __launch_bounds__(256, 2) void k_gemm1(
    const float* __restrict__ h, const unsigned short* __restrict__ WT,
    const float* __restrict__ avec,
    unsigned short* __restrict__ WhT,
    float* __restrict__ E1p, float* __restrict__ E1n,
    float* __restrict__ E2p, float* __restrict__ E2n)
{
  const int bx = blockIdx.x;
  const int b = bx & 7, ng = bx >> 3;
  const int n0 = ng * 32;
  const int t = threadIdx.x;
  const int lane = t & 63, w = t >> 6;
  const int l15 = lane & 15, q = lane >> 4;

  __shared__ __align__(16) unsigned short Wt[256 * 36];  // [f][36] pad
  __shared__ float f1a[32], f2a[32];
  if (t < 32) { f1a[t] = 0.f; f2a[t] = 0.f; }

  f32x4 acc[4][2];
#pragma unroll
  for (int i = 0; i < 4; ++i)
#pragma unroll
    for (int j = 0; j < 2; ++j) acc[i][j] = (f32x4){0.f, 0.f, 0.f, 0.f};

  const size_t hbase = ((size_t)(b * 2048 + n0)) * 512;
  const unsigned short* wtb = WT + (w * 64 + l15) * 512 + q * 8;
  const float* hrow0 = h + hbase + (size_t)l15 * 512 + q * 8;
  const float* hrow1 = h + hbase + (size_t)(16 + l15) * 512 + q * 8;

  // prologue: issue af(0), h(0), h(1)
  bf16x8 afA[4], afN[4];
  float4 hA[4], hB[4], hN[4];
#pragma unroll
  for (int mt = 0; mt < 4; ++mt) afA[mt] = *reinterpret_cast<const bf16x8*>(wtb + mt * 16 * 512);
  hA[0] = *reinterpret_cast<const float4*>(hrow0);
  hA[1] = *reinterpret_cast<const float4*>(hrow0 + 4);
  hA[2] = *reinterpret_cast<const float4*>(hrow1);
  hA[3] = *reinterpret_cast<const float4*>(hrow1 + 4);
  hB[0] = *reinterpret_cast<const float4*>(hrow0 + 32);
  hB[1] = *reinterpret_cast<const float4*>(hrow0 + 36);
  hB[2] = *reinterpret_cast<const float4*>(hrow1 + 32);
  hB[3] = *reinterpret_cast<const float4*>(hrow1 + 36);

#pragma unroll
  for (int k = 0; k < 16; ++k) {
    // issue af(k+1)
    if (k < 15) {
      const unsigned short* p = wtb + (k + 1) * 32;
#pragma unroll
      for (int mt = 0; mt < 4; ++mt) afN[mt] = *reinterpret_cast<const bf16x8*>(p + mt * 16 * 512);
    }
    // issue h(k+2)
    if (k < 14) {
      int o = (k + 2) * 32;
      hN[0] = *reinterpret_cast<const float4*>(hrow0 + o);
      hN[1] = *reinterpret_cast<const float4*>(hrow0 + o + 4);
      hN[2] = *reinterpret_cast<const float4*>(hrow1 + o);
      hN[3] = *reinterpret_cast<const float4*>(hrow1 + o + 4);
    }
    // convert h(k) -> bf16 fragments, MFMA
    bf16x8 bfr[2];
#pragma unroll
    for (int nt = 0; nt < 2; ++nt) {
      float4 x0 = hA[nt * 2], x1 = hA[nt * 2 + 1];
      bf16x8 bb;
      bb[0] = (short)f2bf(x0.x); bb[1] = (short)f2bf(x0.y);
      bb[2] = (short)f2bf(x0.z); bb[3] = (short)f2bf(x0.w);
      bb[4] = (short)f2bf(x1.x); bb[5] = (short)f2bf(x1.y);
      bb[6] = (short)f2bf(x1.z); bb[7] = (short)f2bf(x1.w);
      bfr[nt] = bb;
    }
#pragma unroll
    for (int mt = 0; mt < 4; ++mt)
#pragma unroll
      for (int nt = 0; nt < 2; ++nt)
        acc[mt][nt] = __builtin_amdgcn_mfma_f32_16x16x32_bf16(afA[mt], bfr[nt], acc[mt][nt], 0, 0, 0);
    // rotate stages (folded by unroll)
    if (k < 15) {
#pragma unroll
      for (int mt = 0; mt < 4; ++mt) afA[mt] = afN[mt];
#pragma unroll
      for (int i = 0; i < 4; ++i) hA[i] = hB[i];
#pragma unroll
      for (int i = 0; i < 4; ++i) hB[i] = hN[i];
    }
  }

  // stage into LDS [f][n] + f1/f2 partials
  float s1[2] = {0.f, 0.f}, s2[2] = {0.f, 0.f};
#pragma unroll
  for (int mt = 0; mt < 4; ++mt) {
#pragma unroll
    for (int nt = 0; nt < 2; ++nt) {
#pragma unroll
      for (int r = 0; r < 4; ++r) {
        int f = w * 64 + mt * 16 + q * 4 + r;
        float v = acc[mt][nt][r];
        Wt[f * 36 + nt * 16 + l15] = f2bf(v);
        s1[nt] += v * avec[f];
        s2[nt] += v * avec[256 + f];
      }
    }
  }
#pragma unroll
  for (int nt = 0; nt < 2; ++nt) {
    s1[nt] += __shfl_xor(s1[nt], 16); s1[nt] += __shfl_xor(s1[nt], 32);
    s2[nt] += __shfl_xor(s2[nt], 16); s2[nt] += __shfl_xor(s2[nt], 32);
  }
  __syncthreads();   // Wt visible, f1a/f2a init visible
  if (q == 0) {
#pragma unroll
    for (int nt = 0; nt < 2; ++nt) {
      atomicAdd(&f1a[nt * 16 + l15], s1[nt]);
      atomicAdd(&f2a[nt * 16 + l15], s2[nt]);
    }
  }
  // WhT stores: 8-byte lanes, 64-B segments per f-row
#pragma unroll
  for (int i = 0; i < 8; ++i) {
    int f = i * 32 + (t >> 3), g = t & 7;
    uint2 v = *reinterpret_cast<const uint2*>(Wt + f * 36 + g * 4);
    *reinterpret_cast<uint2*>(WhT + (size_t)(b * 256 + f) * 2048 + n0 + g * 4) = v;
  }
  __syncthreads();   // atomics complete
  if (t < 32) {
    int n = b * 2048 + n0 + t;
    float f1 = f1a[t], f2 = f2a[t];
    E1p[n] = __expf(f1);
    E1n[n] = __expf(GAT_ALPHA * f1);
    E2p[n] = __expf(f2);
    E2n[n] = __expf(GAT_ALPHA * f2);
  }
}

// build one A-fragment (8 cols of one row) and write it in fragment layout
__device__ __forceinline__ void build_frag(
    unsigned short* dst, int4 alo, int4 ahi, float e1p, float e1n,
    float4 epl, float4 eph, float4 enl, float4 enh, float& den)
{
  float p0 = alo.x ? fmaxf(e1p * epl.x, e1n * enl.x) : 0.f;
  float p1 = alo.y ? fmaxf(e1p * epl.y, e1n * enl.y) : 0.f;
  float p2 = alo.z ? fmaxf(e1p * epl.z, e1n * enl.z) : 0.f;
  float p3 = alo.w ? fmaxf(e1p * epl.w, e1n * enl.w) : 0.f;
  float p4 = ahi.x ? fmaxf(e1p * eph.x, e1n * enh.x) : 0.f;
  float p5 = ahi.y ? fmaxf(e1p * eph.y, e1n * enh.y) : 0.f;
  float p6 = ahi.z ? fmaxf(e1p * eph.z, e1n * enh.z) : 0.f;
  float p7 = ahi.w ? fmaxf(e1p * eph.w, e1n * enh.w) : 0.f;
  den += ((p0 + p1) + (p2 + p3)) + ((p4 + p5) + (p6 + p7));
  uint4 pk;
  pk.x = f2bf_u(p0) | (f2bf_u(p1) << 16);
  pk.y = f2bf_u(p2) | (f2bf_u(p3) << 16);
  pk.z = f2bf_u(p4) | (f2bf_u(p5) << 16);
  pk.w = f2bf_u(p6) | (f2bf_u(p7) << 16);
  *reinterpret_cast<uint4*>(dst) = pk;
}

// ---------------- kernel 2: out = elu(softmax-masked P @ Wh), fused -------
// Grid 256 (8 b x 32 row-groups of 64), 512 thr, 1 block/CU.
// Software pipeline: everything consumed in iter c was issued in iter c-1
// and force-arrived by that iteration's barrier drain -> zero stalls in the
// MFMA/construct phases. Full unroll SSA-renames the stage registers.
__global__ __launch_bounds__(512, 2) void k_gat(
    const int* __restrict__ adj, const unsigned short* __restrict__ WhT,
    const float* __restrict__ E1p, const float* __restrict__ E1n,
    const float* __restrict__ E2p, const float* __restrict__ E2n,
    float* __restrict__ out)
{
  const int bx = blockIdx.x;               // 256 blocks = 8 batches x 32 row-groups
  const int b = bx & 7, ig = bx >> 3;
  const int i0 = ig * 64;
  const int t = threadIdx.x;
  const int lane = t & 63, w = t >> 6;
  const int l15 = lane & 15, q = lane >> 4;
  const int m = t & 15, qk = (t >> 4) & 3, pp = t >> 6;
  const int rt0 = pp >> 2, ks = pp & 3;
  const int r0 = rt0 * 16 + m, r1 = r0 + 32;
  const int cb = ks * 32 + qk * 8;

  __shared__ __align__(16) unsigned short Pb[2][8192];  // 16 frags x 64 lanes x 16B
  __shared__ float den_l[64];
  if (t < 64) den_l[t] = 0.f;

  const float e1p0 = E1p[b * 2048 + i0 + r0], e1n0 = E1n[b * 2048 + i0 + r0];
  const float e1p1 = E1p[b * 2048 + i0 + r1], e1n1 = E1n[b * 2048 + i0 + r1];
  float d0 = 0.f, d1 = 0.f;

  f32x4 acc[4][2];
#pragma unroll
  for (int i = 0; i < 4; ++i)
#pragma unroll
    for (int j = 0; j < 2; ++j) acc[i][j] = (f32x4){0.f, 0.f, 0.f, 0.f};

  const size_t adj0 = ((size_t)(b * 2048 + i0 + r0)) * 2048 + cb;
  const size_t adj1 = adj0 + (size_t)32 * 2048;
  const int e2b = b * 2048 + cb;
  const unsigned short* Wb = WhT + (size_t)(b * 256 + w * 32) * 2048;

  // ---- prologue ----
  // chunk 0 raw
  int4 z0l = *reinterpret_cast<const int4*>(adj + adj0);
  int4 z0h = *reinterpret_cast<const int4*>(adj + adj0 + 4);
  int4 z1l = *reinterpret_cast<const int4*>(adj + adj1);
  int4 z1h = *reinterpret_cast<const int4*>(adj + adj1 + 4);
  float4 zpl = *reinterpret_cast<const float4*>(E2p + e2b);
  float4 zph = *reinterpret_cast<const float4*>(E2p + e2b + 4);
  float4 znl = *reinterpret_cast<const float4*>(E2n + e2b);
  float4 znh = *reinterpret_cast<const float4*>(E2n + e2b + 4);
  // B(0), adj(1), e2(1) in flight across the prologue barrier
  bf16x8 bcur[2][4], bnxt[2][4];
#pragma unroll
  for (int ct = 0; ct < 2; ++ct)
#pragma unroll
    for (int k2 = 0; k2 < 4; ++k2)
      bcur[ct][k2] = *reinterpret_cast<const bf16x8*>(
          Wb + (size_t)(ct * 16 + l15) * 2048 + k2 * 32 + q * 8);
  int4 A0l = *reinterpret_cast<const int4*>(adj + adj0 + 128);
  int4 A0h = *reinterpret_cast<const int4*>(adj + adj0 + 132);
  int4 A1l = *reinterpret_cast<const int4*>(adj + adj1 + 128);
  int4 A1h = *reinterpret_cast<const int4*>(adj + adj1 + 132);
  float4 Epl = *reinterpret_cast<const float4*>(E2p + e2b + 128);
  float4 Eph = *reinterpret_cast<const float4*>(E2p + e2b + 132);
  float4 Enl = *reinterpret_cast<const float4*>(E2n + e2b + 128);
  float4 Enh = *reinterpret_cast<const float4*>(E2n + e2b + 132);
  // construct chunk 0 (waits only on the chunk-0 loads; later loads are younger)
  build_frag(&Pb[0][(pp * 64 + lane) * 8], z0l, z0h, e1p0, e1n0, zpl, zph, znl, znh, d0);
  build_frag(&Pb[0][((pp + 8) * 64 + lane) * 8], z1l, z1h, e1p1, e1n1, zpl, zph, znl, znh, d1);
  __syncthreads();

#pragma unroll
  for (int c = 0; c < 16; ++c) {
    // 1. issue B(c+1)
    if (c < 15) {
      const unsigned short* p = Wb + (c + 1) * 128 + q * 8;
#pragma unroll
      for (int ct = 0; ct < 2; ++ct)
#pragma unroll
        for (int k2 = 0; k2 < 4; ++k2)
          bnxt[ct][k2] = *reinterpret_cast<const bf16x8*>(p + (size_t)(ct * 16 + l15) * 2048 + k2 * 32);
    }
    // 2. issue adj(c+2), e2(c+2)
    int4 nA0l, nA0h, nA1l, nA1h;
    float4 nEpl, nEph, nEnl, nEnh;
    if (c < 14) {
      int o = (c + 2) * 128;
      nA0l = *reinterpret_cast<const int4*>(adj + adj0 + o);
      nA0h = *reinterpret_cast<const int4*>(adj + adj0 + o + 4);
      nA1l = *reinterpret_cast<const int4*>(adj + adj1 + o);
      nA1h = *reinterpret_cast<const int4*>(adj + adj1 + o + 4);
      nEpl = *reinterpret_cast<const float4*>(E2p + e2b + o);
      nEph = *reinterpret_cast<const float4*>(E2p + e2b + o + 4);
      nEnl = *reinterpret_cast<const float4*>(E2n + e2b + o);
      nEnh = *reinterpret_cast<const float4*>(E2n + e2b + o + 4);
    }
    // 3. MFMA(c): A from LDS (arrived), B from registers (arrived) -> no waits
    const unsigned short* pb = &Pb[c & 1][0];
#pragma unroll
    for (int k2 = 0; k2 < 4; ++k2) {
      bf16x8 afr[4];
#pragma unroll
      for (int rt = 0; rt < 4; ++rt)
        afr[rt] = *reinterpret_cast<const bf16x8*>(pb + ((rt * 4 + k2) * 64 + lane) * 8);
#pragma unroll
      for (int rt = 0; rt < 4; ++rt)
#pragma unroll
        for (int ct = 0; ct < 2; ++ct)
          acc[rt][ct] = __builtin_amdgcn_mfma_f32_16x16x32_bf16(afr[rt], bcur[ct][k2], acc[rt][ct], 0, 0, 0);
    }
    // 4. construct(c+1) from registers (arrived) -> no waits
    if (c < 15) {
      unsigned short* wb = &Pb[(c + 1) & 1][0];
      build_frag(wb + (pp * 64 + lane) * 8, A0l, A0h, e1p0, e1n0, Epl, Eph, Enl, Enh, d0);
      build_frag(wb + ((pp + 8) * 64 + lane) * 8, A1l, A1h, e1p1, e1n1, Epl, Eph, Enl, Enh, d1);
    }
    // 5. barrier: drains loads issued ~2000 cycles ago at step 1/2
    if (c < 15) __syncthreads();
    // rotate stages (folded into SSA by full unroll)
    if (c < 15) {
#pragma unroll
      for (int ct = 0; ct < 2; ++ct)
#pragma unroll
        for (int k2 = 0; k2 < 4; ++k2) bcur[ct][k2] = bnxt[ct][k2];
    }
    if (c < 14) {
      A0l = nA0l; A0h = nA0h; A1l = nA1l; A1h = nA1h;
      Epl = nEpl; Eph = nEph; Enl = nEnl; Enh = nEnh;
    }
  }

  // denominator: reduce over qk lanes, then 4 row-tile waves combine via LDS
  d0 += __shfl_xor(d0, 16); d0 += __shfl_xor(d0, 32);
  d1 += __shfl_xor(d1, 16); d1 += __shfl_xor(d1, 32);
  if (lane < 16) {
    atomicAdd(&den_l[r0], d0);
    atomicAdd(&den_l[r1], d1);
  }
  __syncthreads();

  // epilogue: out = elu(acc/den); C row = rt*16+q*4+r, col f = w*32+ct*16+l15
#pragma unroll
  for (int rt = 0; rt < 4; ++rt) {
#pragma unroll
    for (int r = 0; r < 4; ++r) {
      int row = rt * 16 + q * 4 + r;
      float dinv = 1.0f / den_l[row];
      size_t ob = ((size_t)(b * 2048 + i0 + row)) * 256 + w * 32;
#pragma unroll
      for (int ct = 0; ct < 2; ++ct) {
        float v = acc[rt][ct][r] * dinv;
        v = v > 0.f ? v : (__expf(v) - 1.f);
        out[ob + ct * 16 + l15] = v;
      }
    }
  }
}

extern "C" void kernel_launch(void* const* d_in, const int* in_sizes, int n_in,
                              void* d_out, int out_size, void* d_ws, size_t ws_size,
                              hipStream_t stream) {
  const float* h   = (const float*)d_in[0];   // [8,2048,512] f32
  const int*   adj = (const int*)d_in[1];     // [8,2048,2048] i32
  const float* W   = (const float*)d_in[2];   // [512,256] f32
  const float* a   = (const float*)d_in[3];   // [512,1] f32
  float* out = (float*)d_out;                 // [8,2048,256] f32

  char* ws = (char*)d_ws;
  unsigned short* WhT = (unsigned short*)ws;                  // 8 MB   [8][256][2048] bf16
  unsigned short* WT  = (unsigned short*)(ws + 8388608);      // 256 KB [256][512] bf16
  float* E1p  = (float*)(ws + 8388608 + 262144);              // 64 KB each
  float* E1n  = E1p + 16384;
  float* E2p  = E1n + 16384;
  float* E2n  = E2p + 16384;

  k_wt<<<dim3(64), dim3(256), 0, stream>>>(W, WT);
  k_gemm1<<<dim3(512), dim3(256), 0, stream>>>(h, WT, a, WhT, E1p, E1n, E2p, E2n);
  k_gat<<<dim3(256), dim3(512), 0, stream>>>(adj, WhT, E1p, E1n, E2p, E2n, out);
}